// Round 3
// baseline (1701.154 us; speedup 1.0000x reference)
//
#include <hip/hip_runtime.h>
#include <hip/hip_bf16.h>

typedef __bf16 bfr;
typedef bfr v8bf __attribute__((ext_vector_type(8)));
typedef bfr v4bf __attribute__((ext_vector_type(4)));
typedef float v4f __attribute__((ext_vector_type(4)));

static constexpr int Bn = 64, H = 256, D = 768;
static constexpr int NR = 100000, ER = 400000;
static constexpr int NC = 100000, EC = 300000, G = 512;
static constexpr int SCAN_CH = 1024;  // elements per scan block

// ---------------- fused prep: 7 weight transposes + zero degs + zero loss ----
// W f32 [K,N] -> Wt bf16 [N,K]
__global__ void prep_all(const float* __restrict__ Wt0, const float* __restrict__ Wv,
                         const float* __restrict__ Wi, const float* __restrict__ Wr1,
                         const float* __restrict__ Wr2, const float* __restrict__ Wc1,
                         const float* __restrict__ Wc2,
                         bfr* __restrict__ Ot, bfr* __restrict__ Ov, bfr* __restrict__ Oi,
                         bfr* __restrict__ Or1, bfr* __restrict__ Or2,
                         bfr* __restrict__ Oc1, bfr* __restrict__ Oc2,
                         int* __restrict__ deg_r, int* __restrict__ deg_c,
                         float* __restrict__ lossw) {
  int i = blockIdx.x * 256 + threadIdx.x;
  if (i == 0) *lossw = 0.0f;
  const int DH = D * H, HH = H * H;
  if (i < 3 * DH) {
    int s = i / DH, j = i - s * DH;
    const float* W = (s == 0) ? Wt0 : (s == 1 ? Wv : Wi);
    bfr* O = (s == 0) ? Ot : (s == 1 ? Ov : Oi);
    int k = j / H, n = j - k * H;
    O[(size_t)n * D + k] = (bfr)W[j];
    return;
  }
  i -= 3 * DH;
  if (i < 4 * HH) {
    int s = i / HH, j = i - s * HH;
    const float* W = (s == 0) ? Wr1 : (s == 1 ? Wr2 : (s == 2 ? Wc1 : Wc2));
    bfr* O = (s == 0) ? Or1 : (s == 1 ? Or2 : (s == 2 ? Oc1 : Oc2));
    int k = j / H, n = j - k * H;
    O[(size_t)n * H + k] = (bfr)W[j];
    return;
  }
  i -= 4 * HH;
  if (i < NR) { deg_r[i] = 0; return; }
  i -= NR;
  if (i < NC) deg_c[i] = 0;
}

// ---------------- small GEMM (M=64 modality projections only) ----------------
// mfma_f32_16x16x32_bf16: A[m=lane&15][k=quad*8+j]; B[k=quad*8+j][n=lane&15];
// D[row=quad*4+r][col=lane&15]   (m89/m91-verified layouts)
__launch_bounds__(256)
__global__ void gemm_k(const float* __restrict__ A, const bfr* __restrict__ Bt,
                       float* __restrict__ Cf, int M, int K, int ldc, int col0) {
  int wid = (int)((blockIdx.x * 256u + threadIdx.x) >> 6);
  int m0 = wid * 16;
  if (m0 >= M) return;
  int lane = threadIdx.x & 63;
  int mrow = lane & 15;
  int quad = lane >> 4;
  const float* Ap = A + (size_t)(m0 + mrow) * K + quad * 8;
  const bfr* Bp = Bt + (size_t)mrow * K + quad * 8;
  v4f acc[16] = {};
  for (int k0 = 0; k0 < K; k0 += 32) {
    v8bf a;
    const float4* p = (const float4*)(Ap + k0);
    float4 x = p[0], y = p[1];
    a[0] = (bfr)x.x; a[1] = (bfr)x.y; a[2] = (bfr)x.z; a[3] = (bfr)x.w;
    a[4] = (bfr)y.x; a[5] = (bfr)y.y; a[6] = (bfr)y.z; a[7] = (bfr)y.w;
#pragma unroll
    for (int nt = 0; nt < 16; ++nt) {
      v8bf b = *(const v8bf*)(Bp + (size_t)nt * 16 * K + k0);
      acc[nt] = __builtin_amdgcn_mfma_f32_16x16x32_bf16(a, b, acc[nt], 0, 0, 0);
    }
  }
#pragma unroll
  for (int nt = 0; nt < 16; ++nt) {
#pragma unroll
    for (int r = 0; r < 4; ++r) {
      int row = m0 + quad * 4 + r;
      int col = col0 + nt * 16 + mrow;
      Cf[(size_t)row * ldc + col] = acc[nt][r];
    }
  }
}

// ---------------- async global->LDS helper ----------------
__device__ __forceinline__ void gld_lds16(const void* g, void* l) {
  __builtin_amdgcn_global_load_lds(
      (const __attribute__((address_space(1))) void*)g,
      (__attribute__((address_space(3))) void*)l, 16, 0, 0);
}

// ---------------- K=768 f32-A tiled GEMM, 2-phase double-buffered ----------
// BM=128, BN=256 (full width), BK=32. 512 threads = 8 waves (2M x 4N),
// each wave a 64x64 sub-tile (4x4 frags). T3 "minimum 2-phase": issue next
// tile's loads, compute current, ds_write A, one barrier per step.
static constexpr int TBM = 128, TBN = 256, TBK = 32;

__launch_bounds__(512)
__global__ void gemm_tile_f(const float* __restrict__ A, const bfr* __restrict__ Bt,
                            bfr* __restrict__ C, int M, int K) {
  __shared__ bfr As[2][TBM * TBK];  // 2 x 8 KB
  __shared__ bfr Bs[2][TBN * TBK];  // 2 x 16 KB
  int m0 = blockIdx.x * TBM;
  int t = threadIdx.x;
  int lane = t & 63;
  int w = t >> 6, wm = w >> 2, wn = w & 3;
  int mrow = lane & 15, quad = lane >> 4;

  // staging addresses (16B chunks)
  int rA = t >> 2, ccA = t & 3;
  int rgA = m0 + rA; if (rgA >= M) rgA = M - 1;  // clamp tail (read-only)
  const float* gAp = A + (size_t)rgA * K + ccA * 8;
  int rB = t >> 2, ccB = t & 3;
  const bfr* gB0 = Bt + (size_t)rB * K + ccB * 8;
  const bfr* gB1 = Bt + (size_t)(128 + rB) * K + ccB * 8;

  int aoffA = wm * 64 + mrow;
  int aoffB = wn * 64 + mrow;

  float4 x, y;
  auto loadA = [&](int k0) {
    const float4* p = (const float4*)(gAp + k0);
    x = p[0]; y = p[1];
  };
  auto stageB = [&](int buf, int k0) {
    gld_lds16(gB0 + k0, (char*)&Bs[buf][0] + (size_t)(w * 64) * 16);
    gld_lds16(gB1 + k0, (char*)&Bs[buf][0] + (size_t)(512 + w * 64) * 16);
  };
  auto writeA = [&](int buf) {
    v8bf v;
    v[0] = (bfr)x.x; v[1] = (bfr)x.y; v[2] = (bfr)x.z; v[3] = (bfr)x.w;
    v[4] = (bfr)y.x; v[5] = (bfr)y.y; v[6] = (bfr)y.z; v[7] = (bfr)y.w;
    *(v8bf*)(&As[buf][0] + (size_t)t * 8) = v;
  };

  loadA(0); stageB(0, 0); writeA(0);
  __syncthreads();  // buf0 ready

  v4f acc[4][4] = {};
  int cur = 0;
  int nsteps = K / TBK;
  for (int ks = 0; ks < nsteps; ++ks) {
    int k0n = (ks + 1) * TBK;
    bool more = k0n < K;
    if (more) { loadA(k0n); stageB(cur ^ 1, k0n); }  // prefetch next tile
    const bfr* pA = &As[cur][0] + (size_t)aoffA * TBK + quad * 8;
    const bfr* pB = &Bs[cur][0] + (size_t)aoffB * TBK + quad * 8;
    v8bf af[4], bv[4];
#pragma unroll
    for (int i2 = 0; i2 < 4; ++i2) af[i2] = *(const v8bf*)(pA + (size_t)i2 * 16 * TBK);
#pragma unroll
    for (int i2 = 0; i2 < 4; ++i2) bv[i2] = *(const v8bf*)(pB + (size_t)i2 * 16 * TBK);
#pragma unroll
    for (int mi = 0; mi < 4; ++mi)
#pragma unroll
      for (int ni = 0; ni < 4; ++ni)
        acc[mi][ni] = __builtin_amdgcn_mfma_f32_16x16x32_bf16(
            af[mi], bv[ni], acc[mi][ni], 0, 0, 0);
    if (more) writeA(cur ^ 1);  // vmcnt wait was hidden by the MFMAs
    __syncthreads();            // publish buf^1 (drains gld_lds too)
    cur ^= 1;
  }

#pragma unroll
  for (int mi = 0; mi < 4; ++mi)
#pragma unroll
    for (int ni = 0; ni < 4; ++ni)
#pragma unroll
      for (int r = 0; r < 4; ++r) {
        int row = m0 + wm * 64 + mi * 16 + quad * 4 + r;
        int col = wn * 64 + ni * 16 + mrow;
        if (row < M) C[(size_t)row * H + col] = (bfr)acc[mi][ni][r];
      }
}

// ---------------- persistent-B GEMM for H x H (K=256) layers ---------------
// Whole B (256x256 bf16 = 128 KiB) staged once into LDS in tile-major layout:
// tile (kt,nt) is a contiguous 1 KB block holding the 64 lanes' 16 B frags at
// chunk (mrow*4+quad) -> every frag ds_read_b128 covers a contiguous 1 KB =
// conflict-free. Zero barriers in the K-loop; A read direct from global.
__launch_bounds__(512, 1)
__global__ void gemm_pB(const bfr* __restrict__ A, const bfr* __restrict__ Bt,
                        bfr* __restrict__ C, int M) {
  __shared__ bfr Bs[65536];  // 128 KiB
  int t = threadIdx.x;
  int lane = t & 63;
  int w = t >> 6;
  int mrow = lane & 15, quad = lane >> 4;

  // stage: 8192 chunks of 16 B, 16 rounds of 512
#pragma unroll
  for (int r = 0; r < 16; ++r) {
    int c = r * 512 + t;
    int T = c >> 6, cw = c & 63;
    int kt = T >> 4, nt = T & 15;
    int tm = cw >> 2, tq = cw & 3;
    const bfr* src = Bt + (size_t)(nt * 16 + tm) * H + kt * 32 + tq * 8;
    gld_lds16(src, (char*)Bs + (size_t)(r * 512 + w * 64) * 16);
  }
  __syncthreads();  // B resident for the whole kernel

  int row = blockIdx.x * 128 + w * 16 + mrow;
  int rclamp = row < M ? row : M - 1;
  const bfr* Ap = A + (size_t)rclamp * H + quad * 8;
  v8bf a[8];
#pragma unroll
  for (int kt = 0; kt < 8; ++kt) a[kt] = *(const v8bf*)(Ap + kt * 32);

  v4f acc[16] = {};
#pragma unroll
  for (int kt = 0; kt < 8; ++kt) {
#pragma unroll
    for (int nt = 0; nt < 16; ++nt) {
      v8bf b = *(const v8bf*)(Bs + ((size_t)(kt * 16 + nt) * 64 + mrow * 4 + quad) * 8);
      acc[nt] = __builtin_amdgcn_mfma_f32_16x16x32_bf16(a[kt], b, acc[nt], 0, 0, 0);
    }
  }

  int orow_base = blockIdx.x * 128 + w * 16 + quad * 4;
#pragma unroll
  for (int nt = 0; nt < 16; ++nt)
#pragma unroll
    for (int r = 0; r < 4; ++r) {
      int orow = orow_base + r;
      if (orow < M) C[(size_t)orow * H + nt * 16 + mrow] = (bfr)acc[nt][r];
    }
}

// ---------------- CSR build ----------------
__global__ void deg_count_i(const int* __restrict__ dst, int* deg, int E) {
  int e = blockIdx.x * blockDim.x + threadIdx.x;
  if (e < E) atomicAdd(deg + dst[e], 1);
}

// hierarchical exclusive scan: deg[n] -> part[n] (chunk-local), bsum per block
// also emits dinv = rsqrt(deg+1)
__global__ void scan1(const int* __restrict__ deg, int* __restrict__ part,
                      int* __restrict__ bsum, float* __restrict__ dinv, int n) {
  __shared__ int tmp[256];
  int t = threadIdx.x;
  int base = blockIdx.x * SCAN_CH + t * 4;
  int v0 = (base + 0 < n) ? deg[base + 0] : 0;
  int v1 = (base + 1 < n) ? deg[base + 1] : 0;
  int v2 = (base + 2 < n) ? deg[base + 2] : 0;
  int v3 = (base + 3 < n) ? deg[base + 3] : 0;
  if (base + 0 < n) dinv[base + 0] = rsqrtf((float)v0 + 1.0f);
  if (base + 1 < n) dinv[base + 1] = rsqrtf((float)v1 + 1.0f);
  if (base + 2 < n) dinv[base + 2] = rsqrtf((float)v2 + 1.0f);
  if (base + 3 < n) dinv[base + 3] = rsqrtf((float)v3 + 1.0f);
  int ls = v0 + v1 + v2 + v3;
  tmp[t] = ls;
  __syncthreads();
  for (int o = 1; o < 256; o <<= 1) {
    int vv = (t >= o) ? tmp[t - o] : 0;
    __syncthreads();
    tmp[t] += vv;
    __syncthreads();
  }
  int off = tmp[t] - ls;
  if (base + 0 < n) part[base + 0] = off;
  if (base + 1 < n) part[base + 1] = off + v0;
  if (base + 2 < n) part[base + 2] = off + v0 + v1;
  if (base + 3 < n) part[base + 3] = off + v0 + v1 + v2;
  if (t == 255) bsum[blockIdx.x] = tmp[255];
}
__global__ void scan2(int* bsum, int nb) {  // in-place exclusive
  if (threadIdx.x == 0 && blockIdx.x == 0) {
    int run = 0;
    for (int b = 0; b < nb; ++b) { int s = bsum[b]; bsum[b] = run; run += s; }
  }
}
__global__ void scan3(int* __restrict__ part, const int* __restrict__ bsum,
                      int* __restrict__ cursor, int n, int E) {
  int i = blockIdx.x * blockDim.x + threadIdx.x;
  if (i < n) { part[i] += bsum[i / SCAN_CH]; cursor[i] = 0; }
  if (i == n) part[n] = E;
}

__global__ void fill_edges(const int* __restrict__ src, const int* __restrict__ dst,
                           const float* __restrict__ dinv, const int* __restrict__ rp,
                           int* __restrict__ cursor, int* __restrict__ esrc,
                           float* __restrict__ ew, int E) {
  int e = blockIdx.x * blockDim.x + threadIdx.x;
  if (e >= E) return;
  int s = src[e], d = dst[e];
  int pos = rp[d] + atomicAdd(cursor + d, 1);
  esrc[pos] = s;
  ew[pos] = dinv[s] * dinv[d];
}

// ---------------- GCN aggregate (gather, no atomics) ----------------
__device__ __forceinline__ void bf4_to_f32(const ushort4 u, float f[4]) {
  f[0] = __uint_as_float((unsigned)u.x << 16);
  f[1] = __uint_as_float((unsigned)u.y << 16);
  f[2] = __uint_as_float((unsigned)u.z << 16);
  f[3] = __uint_as_float((unsigned)u.w << 16);
}
template<bool RELU>
__launch_bounds__(256)
__global__ void gcn_gather(const bfr* __restrict__ h, const int* __restrict__ rp,
                           const int* __restrict__ esrc, const float* __restrict__ ew,
                           const float* __restrict__ dinv,
                           bfr* __restrict__ outB, float* __restrict__ outF, int N) {
  int node = (int)((blockIdx.x * 256u + threadIdx.x) >> 6);
  if (node >= N) return;
  int lane = threadIdx.x & 63;
  const ushort* hp = (const ushort*)h;
  size_t self = (size_t)node * H + lane * 4;
  float di = dinv[node];
  float w0 = di * di;
  float a[4], f[4];
  bf4_to_f32(*(const ushort4*)(hp + self), f);
  a[0] = f[0] * w0; a[1] = f[1] * w0; a[2] = f[2] * w0; a[3] = f[3] * w0;
  int beg = rp[node], end = rp[node + 1];
  for (int j = beg; j < end; ++j) {
    int s = esrc[j];
    float wj = ew[j];
    bf4_to_f32(*(const ushort4*)(hp + (size_t)s * H + lane * 4), f);
    a[0] += f[0] * wj; a[1] += f[1] * wj; a[2] += f[2] * wj; a[3] += f[3] * wj;
  }
  if (RELU) {
    v4bf o;
    o[0] = (bfr)fmaxf(a[0], 0.0f); o[1] = (bfr)fmaxf(a[1], 0.0f);
    o[2] = (bfr)fmaxf(a[2], 0.0f); o[3] = (bfr)fmaxf(a[3], 0.0f);
    *(v4bf*)(outB + self) = o;
  } else {
    float4 o = make_float4(a[0], a[1], a[2], a[3]);
    *(float4*)(outF + self) = o;
  }
}

// ---------------- pooling: sorted seg -> block per segment, no atomics ----
__global__ void pool_seg(const float* __restrict__ x, const int* __restrict__ seg,
                         int n, float* __restrict__ out, int ldo, int col0) {
  int s = blockIdx.x;
  int t = threadIdx.x;
  int lo = 0, hi = n;
  while (lo < hi) { int m = (lo + hi) >> 1; if (seg[m] < s) lo = m + 1; else hi = m; }
  int beg = lo;
  hi = n;
  while (lo < hi) { int m = (lo + hi) >> 1; if (seg[m] < s + 1) lo = m + 1; else hi = m; }
  int end = lo;
  float a0 = 0, a1 = 0, a2 = 0, a3 = 0;
  int r = beg;
  for (; r + 4 <= end; r += 4) {
    a0 += x[(size_t)(r + 0) * H + t];
    a1 += x[(size_t)(r + 1) * H + t];
    a2 += x[(size_t)(r + 2) * H + t];
    a3 += x[(size_t)(r + 3) * H + t];
  }
  for (; r < end; ++r) a0 += x[(size_t)r * H + t];
  float acc = (a0 + a1) + (a2 + a3);
  out[(size_t)s * ldo + col0 + t] = acc / fmaxf((float)(end - beg), 1.0f);
}

// ---------------- head ----------------
__launch_bounds__(256)
__global__ void final_mlp(const float* __restrict__ reps, const float* __restrict__ W1,
                          const float* __restrict__ b1, const float* __restrict__ W2,
                          const float* __restrict__ b2, const int* __restrict__ label,
                          float* __restrict__ out, float* __restrict__ loss_acc) {
  __shared__ float r[5 * H];
  __shared__ float h[H];
  __shared__ float pr[2];
  int b = blockIdx.x;
  int t = threadIdx.x;
  for (int i = t; i < 5 * H; i += 256) r[i] = reps[(size_t)b * (5 * H) + i];
  __syncthreads();
  float acc = b1[t];
  for (int k = 0; k < 5 * H; ++k) acc += r[k] * W1[(size_t)k * H + t];
  h[t] = fmaxf(acc, 0.0f);
  __syncthreads();
  if (t < 2) {
    float p = b2[t];
    for (int k = 0; k < H; ++k) p += h[k] * W2[k * 2 + t];
    pr[t] = p;
  }
  __syncthreads();
  if (t == 0) {
    float p0 = pr[0], p1 = pr[1];
    out[b * 2 + 0] = p0;
    out[b * 2 + 1] = p1;
    float m = fmaxf(p0, p1);
    float lse = m + logf(expf(p0 - m) + expf(p1 - m));
    float lp = (label[b] ? p1 : p0) - lse;
    atomicAdd(loss_acc, -lp * (1.0f / 64.0f));
  }
}
__global__ void loss_write(const float* loss_acc, float* out) {
  out[128] = *loss_acc;
}

// ---------------- host ----------------
extern "C" void kernel_launch(void* const* d_in, const int* in_sizes, int n_in,
                              void* d_out, int out_size, void* d_ws, size_t ws_size,
                              hipStream_t stream) {
  const float* content   = (const float*)d_in[0];
  const float* video     = (const float*)d_in[1];
  const float* image     = (const float*)d_in[2];
  const float* repost_x  = (const float*)d_in[3];
  const float* comment_x = (const float*)d_in[4];
  const float* W_text    = (const float*)d_in[5];
  const float* W_video   = (const float*)d_in[6];
  const float* W_image   = (const float*)d_in[7];
  const float* Wr1       = (const float*)d_in[8];
  const float* Wr2       = (const float*)d_in[9];
  const float* Wc1       = (const float*)d_in[10];
  const float* Wc2       = (const float*)d_in[11];
  const float* W1        = (const float*)d_in[12];
  const float* b1        = (const float*)d_in[13];
  const float* W2        = (const float*)d_in[14];
  const float* b2        = (const float*)d_in[15];
  const int* r_edge      = (const int*)d_in[16];
  const int* r_batch     = (const int*)d_in[17];
  const int* c_edge      = (const int*)d_in[18];
  const int* c_batch     = (const int*)d_in[19];
  const int* cg_batch    = (const int*)d_in[20];
  const int* label       = (const int*)d_in[21];
  float* out = (float*)d_out;

  char* wsb = (char*)d_ws;
  size_t off = 0;
  auto alloc = [&](size_t bytes) -> void* {
    void* p = wsb + off;
    off += (bytes + 255) & ~(size_t)255;
    return p;
  };
  const size_t NH = (size_t)NR * H;  // == NC*H
  bfr*   bufA    = (bfr*)alloc(NH * 2);
  bfr*   bufB    = (bfr*)alloc(NH * 2);
  float* bufC    = (float*)alloc(NH * 4);
  float* dinv    = (float*)alloc(NR * 4);
  int*   deg_r   = (int*)alloc(NR * 4);
  int*   deg_c   = (int*)alloc(NC * 4);
  int*   cursor  = (int*)alloc(NR * 4);
  int*   row_ptr = (int*)alloc((NR + 1) * 4);
  int*   esrc    = (int*)alloc((size_t)ER * 4);
  float* ew      = (float*)alloc((size_t)ER * 4);
  int*   bsum    = (int*)alloc(128 * 4);
  bfr*   Wt_t    = (bfr*)alloc((size_t)D * H * 2);
  bfr*   Wt_v    = (bfr*)alloc((size_t)D * H * 2);
  bfr*   Wt_i    = (bfr*)alloc((size_t)D * H * 2);
  bfr*   Wt_r1   = (bfr*)alloc((size_t)H * H * 2);
  bfr*   Wt_r2   = (bfr*)alloc((size_t)H * H * 2);
  bfr*   Wt_c1   = (bfr*)alloc((size_t)H * H * 2);
  bfr*   Wt_c2   = (bfr*)alloc((size_t)H * H * 2);
  float* reps    = (float*)alloc((size_t)Bn * 5 * H * 4);
  float* graphs  = (float*)alloc((size_t)G * H * 4);
  float* lossw   = (float*)alloc(4);
  (void)ws_size; (void)n_in; (void)in_sizes; (void)out_size;

  const int T = 256;
  auto cdiv = [](int a, int b) { return (a + b - 1) / b; };

  {
    int total = 3 * D * H + 4 * H * H + NR + NC;
    prep_all<<<cdiv(total, T), T, 0, stream>>>(
        W_text, W_video, W_image, Wr1, Wr2, Wc1, Wc2,
        Wt_t, Wt_v, Wt_i, Wt_r1, Wt_r2, Wt_c1, Wt_c2,
        deg_r, deg_c, lossw);
  }

  auto gemm_small = [&](const float* A, const bfr* Bt, float* Cf,
                        int M, int K, int ldc, int col0) {
    gemm_k<<<cdiv(M / 16, 4), T, 0, stream>>>(A, Bt, Cf, M, K, ldc, col0);
  };
  auto gemm_big_f = [&](const float* A, const bfr* Bt, bfr* C, int M, int K) {
    gemm_tile_f<<<cdiv(M, TBM), 512, 0, stream>>>(A, Bt, C, M, K);
  };
  auto gemm_big_b = [&](const bfr* A, const bfr* Bt, bfr* C, int M) {
    gemm_pB<<<cdiv(M, 128), 512, 0, stream>>>(A, Bt, C, M);
  };
  auto build_csr = [&](const int* edge, int* deg, int N, int E) {
    int nb = cdiv(N, SCAN_CH);
    deg_count_i<<<cdiv(E, T), T, 0, stream>>>(edge + E, deg, E);
    scan1<<<nb, T, 0, stream>>>(deg, row_ptr, bsum, dinv, N);
    scan2<<<1, 64, 0, stream>>>(bsum, nb);
    scan3<<<cdiv(N + 1, T), T, 0, stream>>>(row_ptr, bsum, cursor, N, E);
    fill_edges<<<cdiv(E, T), T, 0, stream>>>(edge, edge + E, dinv, row_ptr,
                                             cursor, esrc, ew, E);
  };
  auto gather_relu = [&](const bfr* h, bfr* o, int N) {
    gcn_gather<true><<<cdiv(N, 4), T, 0, stream>>>(h, row_ptr, esrc, ew, dinv,
                                                   o, nullptr, N);
  };
  auto gather_f32 = [&](const bfr* h, float* o, int N) {
    gcn_gather<false><<<cdiv(N, 4), T, 0, stream>>>(h, row_ptr, esrc, ew, dinv,
                                                    nullptr, o, N);
  };

  // modality GEMMs straight into reps
  gemm_small(content, Wt_t, reps, Bn, D, 5 * H, 0 * H);
  gemm_small(video,   Wt_v, reps, Bn, D, 5 * H, 3 * H);
  gemm_small(image,   Wt_i, reps, Bn, D, 5 * H, 4 * H);

  // ---- repost branch ----
  gemm_big_f(repost_x, Wt_t, bufA, NR, D);
  build_csr(r_edge, deg_r, NR, ER);
  gemm_big_b(bufA, Wt_r1, bufB, NR);
  gather_relu(bufB, bufA, NR);
  gemm_big_b(bufA, Wt_r2, bufB, NR);
  gather_f32(bufB, bufC, NR);
  pool_seg<<<Bn, H, 0, stream>>>(bufC, r_batch, NR, reps, 5 * H, 1 * H);

  // ---- comment branch ----
  gemm_big_f(comment_x, Wt_t, bufA, NC, D);
  build_csr(c_edge, deg_c, NC, EC);
  gemm_big_b(bufA, Wt_c1, bufB, NC);
  gather_relu(bufB, bufA, NC);
  gemm_big_b(bufA, Wt_c2, bufB, NC);
  gather_f32(bufB, bufC, NC);
  pool_seg<<<G, H, 0, stream>>>(bufC, c_batch, NC, graphs, H, 0);
  pool_seg<<<Bn, H, 0, stream>>>(graphs, cg_batch, G, reps, 5 * H, 2 * H);

  // ---- head ----
  final_mlp<<<Bn, T, 0, stream>>>(reps, W1, b1, W2, b2, label, out, lossw);
  loss_write<<<1, 1, 0, stream>>>(lossw, out);
}